// Round 9
// baseline (134.429 us; speedup 1.0000x reference)
//
#include <hip/hip_runtime.h>

// Problem constants
#define Gn 256
#define Nn 512
#define En 4096
#define Fn 64
#define Cn 16
#define ET (En + Nn)        // 4608 CSR slots incl self-loops
#define EPAD 4616           // per-graph epk stride in ws (u32 units)

typedef _Float16 halfv8 __attribute__((ext_vector_type(8)));
typedef _Float16 halfv4 __attribute__((ext_vector_type(4)));
typedef float    f32x4  __attribute__((ext_vector_type(4)));

__device__ __forceinline__ float pk_norm(unsigned p) {
    return (float)__builtin_bit_cast(_Float16, (unsigned short)(p & 0xffffu));
}

// ---------------- K0a: x fp32 -> f16 ----------------
__global__ __launch_bounds__(256) void cvt_x(const float* __restrict__ x,
                                             _Float16* __restrict__ xc) {
    size_t base = (size_t)blockIdx.x * 256 + threadIdx.x;   // 2048 blocks
    #pragma unroll
    for (int it = 0; it < 4; ++it) {
        size_t i = base + (size_t)it * (2048 * 256);        // float4 idx, 2M total
        float4 v = ((const float4*)x)[i];
        halfv4 h; h[0]=(_Float16)v.x; h[1]=(_Float16)v.y;
                  h[2]=(_Float16)v.z; h[3]=(_Float16)v.w;
        ((halfv4*)xc)[i] = h;
    }
}

// ---------------- K0b: lw fp32 -> f16, PERMUTED to match h frag layout --------
// flat16 = jobidx*256 + q*64 + m*4 + e ; jobidx = tm*4+to ; n = tm*16+m ;
// o = to*16 + q*4 + e.  K1b writes h in this order; dot is perm-invariant.
__global__ __launch_bounds__(256) void cvt_lw_perm(const float* __restrict__ lw,
                                                   _Float16* __restrict__ lwh) {
    int u = blockIdx.x * 256 + threadIdx.x;   // 512 blocks -> 131072 units of 4
    int c = u >> 13, v = u & 8191;
    int jobidx = v >> 6, q = (v >> 4) & 3, m = v & 15;
    int n = (jobidx >> 2) * 16 + m;
    int o = (jobidx & 3) * 16 + q * 4;
    float4 f = *(const float4*)(lw + (size_t)c * (Nn * Fn) + n * 64 + o);
    halfv4 h; h[0]=(_Float16)f.x; h[1]=(_Float16)f.y;
              h[2]=(_Float16)f.z; h[3]=(_Float16)f.w;
    *(halfv4*)(lwh + (size_t)c * (Nn * Fn) + (size_t)v * 4) = h;
}

// ---------------- K1a: per-graph CSR build -> ws ----------------
__global__ __launch_bounds__(256) void build_csr(const int* __restrict__ ei,
                                                 unsigned* __restrict__ epkG,
                                                 int* __restrict__ cntG) {
    __shared__ int      degL[Nn];
    __shared__ float    dinvL[Nn];
    __shared__ int      cntE[Nn];
    __shared__ unsigned epkL[ET];
    __shared__ int      wsum[4];
    const int g = blockIdx.x, tid = threadIdx.x;
    const int lane = tid & 63, wid = tid >> 6;
    const int* es = ei + (size_t)g * 2 * En;
    const int* ed = es + En;

    degL[tid] = 0; degL[tid + 256] = 0;
    __syncthreads();
    for (int e = tid; e < En; e += 256) atomicAdd(&degL[ed[e]], 1);
    __syncthreads();

    const int t2 = tid * 2;
    int cA = degL[t2] + 1, cB = degL[t2 + 1] + 1;   // slots incl self-loop
    dinvL[t2]     = rsqrtf((float)cA);
    dinvL[t2 + 1] = rsqrtf((float)cB);
    int p = cA + cB, v = p;
    #pragma unroll
    for (int off = 1; off < 64; off <<= 1) {
        int u = __shfl_up(v, off, 64);
        if (lane >= off) v += u;
    }
    if (lane == 63) wsum[wid] = v;
    __syncthreads();
    if (tid == 0) { int a = 0; for (int i = 0; i < 4; ++i) { int t = wsum[i]; wsum[i] = a; a += t; } }
    __syncthreads();
    int pe = v - p + wsum[wid];                     // exclusive prefix at node t2
    cntE[t2] = pe;
    cntE[t2 + 1] = pe + cA;
    __syncthreads();

    for (int e = tid; e < ET; e += 256) {
        int s, t;
        if (e < En) { s = es[e]; t = ed[e]; } else { s = t = e - En; }
        float nrm = dinvL[s] * dinvL[t];
        int slot = atomicAdd(&cntE[t], 1);          // cntE becomes inclusive
        unsigned short nb = __builtin_bit_cast(unsigned short, (_Float16)nrm);
        epkL[slot] = ((unsigned)s << 16) | nb;
    }
    __syncthreads();

    for (int i = tid; i < ET; i += 256) epkG[(size_t)g * EPAD + i] = epkL[i];
    cntG[(size_t)g * Nn + t2]     = cntE[t2];
    cntG[(size_t)g * Nn + t2 + 1] = cntE[t2 + 1];
}

// ---------------- K1b: gather (x from L2) + MFMA conv -> frag-ordered h ------
// 512 blocks (2 per graph, 256 targets each) x 512 thr, ~60 KB LDS ->
// 2 blocks/CU: one block's barrier stalls hide under the other's work
// (R8's 1-block/CU chain exposed ~30us of stall).
__global__ __launch_bounds__(512, 4) void agg_conv(
    const _Float16* __restrict__ xc,   // ws: [G,N,64] f16
    const unsigned* __restrict__ epkG, // ws: [G][EPAD]
    const int*      __restrict__ cntG, // ws: [G][N] inclusive
    const float*    __restrict__ w,    // [64,64]
    const float*    __restrict__ wbias,
    _Float16* __restrict__ hout)       // ws: [G][32768] f16, frag-permuted
{
    __shared__ unsigned short xhs[256 * Fn];  // 32 KB aggregated, swizzled
    __shared__ unsigned short wts[Fn * Fn];   // 8 KB w rows, swizzled
    __shared__ unsigned epkL[ET + 16];        // 18.5 KB (worst-case half)
    __shared__ int cntl[260];
    const int hh = blockIdx.x, g = blockIdx.y;
    const int tid = threadIdx.x, lane = tid & 63, wid = tid >> 6;
    const int tbase = hh * 256;

    const int slotlo = (hh == 0) ? 0 : cntG[(size_t)g * Nn + tbase - 1];
    const int slothi = cntG[(size_t)g * Nn + tbase + 255];
    const int total  = slothi - slotlo;

    if (tid < 257)
        cntl[tid] = (tid == 0) ? slotlo : cntG[(size_t)g * Nn + tbase + tid - 1];
    for (int i = tid; i < total; i += 512)
        epkL[i] = epkG[(size_t)g * EPAD + slotlo + i];
    {   // stage w, swizzled 16B blocks: row o, block b8 -> (b8 ^ (o&7))
        int o = tid >> 3, b8 = tid & 7;
        float4 va = *(const float4*)(w + o * Fn + b8 * 8);
        float4 vb = *(const float4*)(w + o * Fn + b8 * 8 + 4);
        halfv8 hv; hv[0]=(_Float16)va.x; hv[1]=(_Float16)va.y;
                   hv[2]=(_Float16)va.z; hv[3]=(_Float16)va.w;
                   hv[4]=(_Float16)vb.x; hv[5]=(_Float16)vb.y;
                   hv[6]=(_Float16)vb.z; hv[7]=(_Float16)vb.w;
        *(halfv8*)((char*)wts + o * 128 + ((b8 ^ (o & 7)) * 16)) = hv;
    }
    __syncthreads();

    // ---- gather: quarter-wave per local target; x rows from global (L2) ----
    {
        const _Float16* xgc = xc + (size_t)g * (Nn * Fn);
        const int qid = lane >> 4, fl = lane & 15;
        for (int r = 0; r < 8; ++r) {
            int tl = r * 32 + wid * 4 + qid;          // local target 0..255
            int beg = cntl[tl] - slotlo;
            int end = cntl[tl + 1] - slotlo;
            float a0 = 0.f, a1 = 0.f, a2 = 0.f, a3 = 0.f;
            unsigned pA0 = epkL[beg],     pA1 = epkL[beg + 1];
            unsigned pA2 = epkL[beg + 2], pA3 = epkL[beg + 3];
            int j = beg;
            for (; j + 4 <= end; j += 4) {
                unsigned pB0 = epkL[j + 4], pB1 = epkL[j + 5];
                unsigned pB2 = epkL[j + 6], pB3 = epkL[j + 7];
                int s0 = pA0 >> 16, s1 = pA1 >> 16, s2 = pA2 >> 16, s3 = pA3 >> 16;
                float n0 = pk_norm(pA0), n1 = pk_norm(pA1);
                float n2 = pk_norm(pA2), n3 = pk_norm(pA3);
                halfv4 x0 = *(const halfv4*)(xgc + s0 * Fn + fl * 4);
                halfv4 x1 = *(const halfv4*)(xgc + s1 * Fn + fl * 4);
                halfv4 x2 = *(const halfv4*)(xgc + s2 * Fn + fl * 4);
                halfv4 x3 = *(const halfv4*)(xgc + s3 * Fn + fl * 4);
                a0 += n0 * (float)x0[0] + n1 * (float)x1[0] + n2 * (float)x2[0] + n3 * (float)x3[0];
                a1 += n0 * (float)x0[1] + n1 * (float)x1[1] + n2 * (float)x2[1] + n3 * (float)x3[1];
                a2 += n0 * (float)x0[2] + n1 * (float)x1[2] + n2 * (float)x2[2] + n3 * (float)x3[2];
                a3 += n0 * (float)x0[3] + n1 * (float)x1[3] + n2 * (float)x2[3] + n3 * (float)x3[3];
                pA0 = pB0; pA1 = pB1; pA2 = pB2; pA3 = pB3;
            }
            for (; j < end; ++j) {
                int s = pA0 >> 16;
                float nm = pk_norm(pA0);
                halfv4 xv = *(const halfv4*)(xgc + s * Fn + fl * 4);
                a0 += nm * (float)xv[0]; a1 += nm * (float)xv[1];
                a2 += nm * (float)xv[2]; a3 += nm * (float)xv[3];
                pA0 = pA1; pA1 = pA2; pA2 = pA3;
            }
            halfv4 hv; hv[0]=(_Float16)a0; hv[1]=(_Float16)a1;
                       hv[2]=(_Float16)a2; hv[3]=(_Float16)a3;
            int dw = tl * 32 + (((fl >> 1) ^ (tl & 7)) * 4) + (fl & 1) * 2;
            *(halfv4*)((char*)xhs + dw * 4) = hv;
        }
    }
    __syncthreads();

    // ---- conv: D[o][n] tiles via MFMA; store h frag-ordered (coalesced) ----
    {
        const int m = lane & 15, q = lane >> 4;
        #pragma unroll
        for (int j = 0; j < 8; ++j) {
            int idx = wid * 8 + j;                    // 64 jobs: 16 tm x 4 to
            int tm = idx >> 2, to = idx & 3;
            int n = tm * 16 + m;                      // local node
            int o = to * 16 + m;
            halfv8 X0 = *(const halfv8*)((const char*)xhs + n * 128 + ((q       ^ (n & 7)) * 16));
            halfv8 X1 = *(const halfv8*)((const char*)xhs + n * 128 + (((4 + q) ^ (n & 7)) * 16));
            halfv8 W0 = *(const halfv8*)((const char*)wts + o * 128 + ((q       ^ (o & 7)) * 16));
            halfv8 W1 = *(const halfv8*)((const char*)wts + o * 128 + (((4 + q) ^ (o & 7)) * 16));
            f32x4 acc = {0.f, 0.f, 0.f, 0.f};
            acc = __builtin_amdgcn_mfma_f32_16x16x32_f16(W0, X0, acc, 0, 0, 0);
            acc = __builtin_amdgcn_mfma_f32_16x16x32_f16(W1, X1, acc, 0, 0, 0);
            float4 bq = *(const float4*)&wbias[to * 16 + q * 4];
            halfv4 hv;
            hv[0] = (_Float16)fmaxf(acc[0] + bq.x, 0.0f);
            hv[1] = (_Float16)fmaxf(acc[1] + bq.y, 0.0f);
            hv[2] = (_Float16)fmaxf(acc[2] + bq.z, 0.0f);
            hv[3] = (_Float16)fmaxf(acc[3] + bq.w, 0.0f);
            // frag order: jobidx_global = (hh*16+tm)*4+to; offset = jobidx*256+lane*4
            size_t off = (size_t)g * (Nn * Fn)
                       + (size_t)(((hh * 16 + tm) * 4 + to) * 256 + lane * 4);
            *(halfv4*)(hout + off) = hv;              // 512B/wave, coalesced
        }
    }
}

// ---------------- K2: logits partials via MFMA over permuted k ----------------
__global__ __launch_bounds__(256) void linear_mfma(
    const _Float16* __restrict__ h,    // ws: [256][32768] f16 (permuted)
    const _Float16* __restrict__ lwh,  // ws: [16][32768] f16 (same perm)
    float* __restrict__ part)          // ws: [256][32][16]
{
    __shared__ float red[4][64][4];
    const int cx = blockIdx.x, gy = blockIdx.y;
    const int tid = threadIdx.x, lane = tid & 63, wid = tid >> 6;
    const int ml = lane & 15, q = lane >> 4;
    const size_t kbase = (size_t)cx * 1024 + wid * 256;
    const _Float16* ha = h   + (size_t)(gy * 16 + ml) * (Nn * Fn) + kbase + q * 8;
    const _Float16* lb = lwh + (size_t)ml * (Nn * Fn) + kbase + q * 8;

    f32x4 acc = {0.f, 0.f, 0.f, 0.f};
    #pragma unroll
    for (int ks = 0; ks < 8; ++ks) {
        halfv8 a = *(const halfv8*)(ha + ks * 32);
        halfv8 b = *(const halfv8*)(lb + ks * 32);
        acc = __builtin_amdgcn_mfma_f32_16x16x32_f16(a, b, acc, 0, 0, 0);
    }
    #pragma unroll
    for (int r = 0; r < 4; ++r) red[wid][lane][r] = acc[r];
    __syncthreads();
    {
        int m = tid >> 4, cc = tid & 15;      // D: row=(lane>>4)*4+reg, col=lane&15
        int sl = (m >> 2) * 16 + cc, rg = m & 3;
        float v = red[0][sl][rg] + red[1][sl][rg] + red[2][sl][rg] + red[3][sl][rg];
        part[((size_t)(gy * 16 + m) * 32 + cx) * Cn + cc] = v;
    }
}

// ---------------- K3: reduce 32 slices + bias + log_softmax ----------------
__global__ __launch_bounds__(64) void gcn_softmax(
    const float* __restrict__ part, const float* __restrict__ lbias,
    float* __restrict__ out)
{
    const int g = blockIdx.x, lane = threadIdx.x;
    if (lane < Cn) {
        float v = lbias[lane];
        #pragma unroll
        for (int s = 0; s < 32; ++s) v += part[((size_t)g * 32 + s) * Cn + lane];
        float m = v;
        #pragma unroll
        for (int off = 8; off > 0; off >>= 1) m = fmaxf(m, __shfl_xor(m, off, 16));
        float ex = expf(v - m);
        float ssum = ex;
        #pragma unroll
        for (int off = 8; off > 0; off >>= 1) ssum += __shfl_xor(ssum, off, 16);
        out[g * Cn + lane] = v - m - logf(ssum);
    }
}

extern "C" void kernel_launch(void* const* d_in, const int* in_sizes, int n_in,
                              void* d_out, int out_size, void* d_ws, size_t ws_size,
                              hipStream_t stream) {
    const float* x  = (const float*)d_in[0];
    const int*   ei = (const int*)d_in[1];
    const float* w  = (const float*)d_in[2];
    const float* wb = (const float*)d_in[3];
    const float* lw = (const float*)d_in[4];
    const float* lb = (const float*)d_in[5];
    float* out = (float*)d_out;

    char* wsp = (char*)d_ws;
    _Float16* xc   = (_Float16*)(wsp);                       // 16,777,216 B
    _Float16* lwh  = (_Float16*)(wsp + 16777216);            //  1,048,576 B
    unsigned* epkG = (unsigned*)(wsp + 17825792);            //  4,726,784 B
    int*      cntG = (int*)     (wsp + 22552576);            //    524,288 B
    _Float16* hbuf = (_Float16*)(wsp + 23076864);            // 16,777,216 B
    float*    part = (float*)   (wsp + 39854080);            //    524,288 B

    hipLaunchKernelGGL(cvt_x,       dim3(2048),    dim3(256), 0, stream, x, xc);
    hipLaunchKernelGGL(cvt_lw_perm, dim3(512),     dim3(256), 0, stream, lw, lwh);
    hipLaunchKernelGGL(build_csr,   dim3(Gn),      dim3(256), 0, stream, ei, epkG, cntG);
    hipLaunchKernelGGL(agg_conv,    dim3(2, Gn),   dim3(512), 0, stream,
                       xc, epkG, cntG, w, wb, hbuf);
    hipLaunchKernelGGL(linear_mfma, dim3(32, 16),  dim3(256), 0, stream,
                       hbuf, lwh, part);
    hipLaunchKernelGGL(gcn_softmax, dim3(Gn),      dim3(64),  0, stream,
                       part, lb, out);
}